// Round 12
// baseline (289.205 us; speedup 1.0000x reference)
//
#include <hip/hip_runtime.h>
#include <stdint.h>

using f32x4  = __attribute__((ext_vector_type(4))) float;
using short8 = __attribute__((ext_vector_type(8))) short;
typedef unsigned short u16;
typedef unsigned int   u32;

// B=8, H=8, L=1024, DM=512, DK=DV=64.  M = B*L = 8192.

static __device__ __forceinline__ u16 f2bf(float f) {
  union { float f; u32 u; } v; v.f = f;
  u32 r = v.u + 0x7fffu + ((v.u >> 16) & 1u);   // RNE
  return (u16)(r >> 16);
}
static __device__ __forceinline__ float bf2f(u16 u) {
  union { u32 u; float f; } v; v.u = ((u32)u) << 16;
  return v.f;
}
static __device__ __forceinline__ float fexp2(float x) {
  float r;
  asm("v_exp_f32 %0, %1" : "=v"(r) : "v"(x));
  return r;
}
static __device__ __forceinline__ u32 cvtpk(float a, float b) {
  u32 r;
  asm("v_cvt_pk_bf16_f32 %0, %1, %2" : "=v"(r) : "v"(a), "v"(b));
  return r;
}

// async global->LDS, 16B per lane; LDS dest = wave-uniform base + lane*16
#define GLDS16(g, l) __builtin_amdgcn_global_load_lds( \
    (const __attribute__((address_space(1))) u32*)(g), \
    (__attribute__((address_space(3))) u32*)(l), 16, 0, 0)

// ---------------- preprocessing ----------------
// blocks [0,1024): weight transposes W[512k][512n] -> Wt[n][k] bf16 (4 mats)
// blocks [1024,1068): rel embeddings relk80/relvT
__global__ __launch_bounds__(256) void k_pre(
    const float* __restrict__ W0, const float* __restrict__ W1,
    const float* __restrict__ W2, const float* __restrict__ W3,
    u16* __restrict__ T0, u16* __restrict__ T1, u16* __restrict__ T2, u16* __restrict__ T3,
    const float* __restrict__ rk, const float* __restrict__ rv,
    u16* __restrict__ relk80, u16* __restrict__ relvT) {
  __shared__ float t[32][33];
  int bid = blockIdx.x, tid = threadIdx.x;
  if (bid < 1024) {
    int mat = bid >> 8, rem = bid & 255;
    const float* W = (mat == 0) ? W0 : (mat == 1) ? W1 : (mat == 2) ? W2 : W3;
    u16* T = (mat == 0) ? T0 : (mat == 1) ? T1 : (mat == 2) ? T2 : T3;
    int tx = tid & 31, ty = tid >> 5;
    int x0 = (rem & 15) * 32, y0 = (rem >> 4) * 32;
    #pragma unroll
    for (int i = 0; i < 4; i++)
      t[ty + i*8][tx] = W[(y0 + ty + i*8) * 512 + (x0 + tx)];
    __syncthreads();
    #pragma unroll
    for (int i = 0; i < 4; i++)
      T[(x0 + ty + i*8) * 512 + (y0 + tx)] = f2bf(t[tx][ty + i*8]);
  } else {
    int i = (bid - 1024) * 256 + tid;
    if (i < 80*64) {
      int row = i >> 6;
      relk80[i] = (row < 65) ? f2bf(rk[i]) : (u16)0;
    }
    int j = i - 80*64;
    if (j >= 0 && j < 64*96) {
      int dv = j / 96, bk = j % 96;
      relvT[j] = (bk < 65) ? f2bf(rv[bk*64 + dv]) : (u16)0;
    }
  }
}

// ---- R16: QKV GEMM (fp32 A, cvt fused) + pack in ONE launch.
// Blocks [0,768): GEMM tiles. Blocks [768,1792): pack, GRID-STRIDE x8 with
// a 2-deep software pipeline (loads for iter j+1 issued before the store of
// iter j). R15's pack was 8192 single-shot blocks: one load-set in flight
// per block lifetime, 4 blocks/CU (34KB static LDS) -> latency-bound at
// 2.57 TB/s, VALUBusy 9%. Pipelined streaming converts it to BW-bound.
struct FArg { const float* A; const u16* Wt; const float* bias; void* out; int mode; float scale; };
struct GArg { const u16* A; const u16* Wt; const float* bias; void* out; int mode; float scale; };

__global__ __launch_bounds__(256, 3) void k_gemmf(FArg g0, FArg g1, FArg g2,
    const int* __restrict__ rm, const float* __restrict__ rw,
    const unsigned char* __restrict__ mk, u32* __restrict__ outp) {
  int bid = blockIdx.x, tid = threadIdx.x;
  if (bid >= 768) {
    // pack: 1024 blocks x 256 threads x 8 iters of uint4 = 8M elements
    int g = (bid - 768) * 256 + tid;           // group index, stride 262144
    const int4*   rm4 = (const int4*)rm;
    const float4* rw4 = (const float4*)rw;
    const uchar4* mk4 = (const uchar4*)mk;
    uint4* out4 = (uint4*)outp;
    int4 r0 = rm4[g]; float4 w0 = rw4[g]; uchar4 m0 = mk4[g];
    #pragma unroll
    for (int it = 0; it < 8; it++) {
      int4 r1; float4 w1; uchar4 m1;
      int gn = g + 262144;
      if (it < 7) { r1 = rm4[gn]; w1 = rw4[gn]; m1 = mk4[gn]; }
      uint4 o;
      o.x = (u32)(r0.x & 63) | (m0.x ? 128u : 0u) | ((u32)f2bf(w0.x) << 16);
      o.y = (u32)(r0.y & 63) | (m0.y ? 128u : 0u) | ((u32)f2bf(w0.y) << 16);
      o.z = (u32)(r0.z & 63) | (m0.z ? 128u : 0u) | ((u32)f2bf(w0.z) << 16);
      o.w = (u32)(r0.w & 63) | (m0.w ? 128u : 0u) | ((u32)f2bf(w0.w) << 16);
      out4[g] = o;
      g = gn; r0 = r1; w0 = w1; m0 = m1;
    }
    return;
  }
  FArg ar = (bid < 256) ? g0 : (bid < 512) ? g1 : g2;
  __shared__ char smem_[34816];
  u16* As = (u16*)smem_;             // [2][4096] u16
  u16* Bs = (u16*)(smem_ + 16384);   // [2][4096] u16
  u16* Cs = (u16*)smem_;             // epilogue staging [128][136] (after barrier)
  int lane = tid & 63, wv = tid >> 6;
  int quad = lane >> 4, l15 = lane & 15;
  int n0 = (bid & 3) * 128, m0 = ((bid >> 2) & 63) * 128;
  int wm = (wv >> 1) * 64, wn = (wv & 1) * 64;
  f32x4 acc[4][4];
  #pragma unroll
  for (int i = 0; i < 4; i++)
    #pragma unroll
    for (int j = 0; j < 4; j++)
      acc[i][j] = (f32x4){0.f, 0.f, 0.f, 0.f};

  const float* Asrc = ar.A + (size_t)(m0 + (tid >> 1)) * 512 + (tid & 1) * 16;
  const u16* Bbase = ar.Wt + (size_t)n0 * 512;
  int c0 = wv * 128;

  float4 fA0[4], fA1[4];
#define LOADA(fa, kt) do { _Pragma("unroll") \
    for (int i = 0; i < 4; i++) fa[i] = *(const float4*)(Asrc + (kt)*32 + i*4); } while (0)
#define WRITEA(fa, nb) do { \
    u32 w0 = cvtpk(fa[0].x, fa[0].y), w1 = cvtpk(fa[0].z, fa[0].w); \
    u32 w2 = cvtpk(fa[1].x, fa[1].y), w3 = cvtpk(fa[1].z, fa[1].w); \
    u32 w4 = cvtpk(fa[2].x, fa[2].y), w5 = cvtpk(fa[2].z, fa[2].w); \
    u32 w6 = cvtpk(fa[3].x, fa[3].y), w7 = cvtpk(fa[3].z, fa[3].w); \
    ((uint4*)&As[(nb)*4096 + tid*16])[0] = make_uint4(w0, w1, w2, w3); \
    ((uint4*)&As[(nb)*4096 + tid*16])[1] = make_uint4(w4, w5, w6, w7); } while (0)
#define GLDSB(kt, nb) do { _Pragma("unroll") \
    for (int i = 0; i < 2; i++) { \
      int c = c0 + i*64 + lane; \
      GLDS16(Bbase + (c >> 2)*512 + (kt)*32 + (c & 3)*8, &Bs[(nb)*4096 + (c0 + i*64)*8]); \
    } } while (0)
#define MFMAS(nb) do { \
    int bs = (nb) * 4096; \
    short8 af[4], bf[4]; \
    _Pragma("unroll") \
    for (int i = 0; i < 4; i++) af[i] = *(const short8*)&As[bs + (wm + i*16 + l15)*32 + quad*8]; \
    _Pragma("unroll") \
    for (int j = 0; j < 4; j++) bf[j] = *(const short8*)&Bs[bs + (wn + j*16 + l15)*32 + quad*8]; \
    __builtin_amdgcn_s_setprio(1); \
    _Pragma("unroll") \
    for (int i = 0; i < 4; i++) \
      _Pragma("unroll") \
      for (int j = 0; j < 4; j++) \
        acc[i][j] = __builtin_amdgcn_mfma_f32_16x16x32_bf16(af[i], bf[j], acc[i][j], 0, 0, 0); \
    __builtin_amdgcn_s_setprio(0); } while (0)

  // prologue: tile0 staged; tile1 A-data in flight
  LOADA(fA0, 0);
  WRITEA(fA0, 0);
  GLDSB(0, 0);
  LOADA(fA1, 1);

  #pragma unroll 2
  for (int ks = 0; ks < 16; ks++) {
    __syncthreads();                   // buf(ks) ready (glds + ds_writes drained)
    if (ks & 1) {
      if (ks < 15) { WRITEA(fA0, (ks + 1) & 1); GLDSB(ks + 1, (ks + 1) & 1); }
      if (ks < 14) LOADA(fA1, ks + 2);
    } else {
      if (ks < 15) { WRITEA(fA1, (ks + 1) & 1); GLDSB(ks + 1, (ks + 1) & 1); }
      if (ks < 14) LOADA(fA0, ks + 2);
    }
    MFMAS(ks & 1);
  }
#undef LOADA
#undef WRITEA
#undef GLDSB
#undef MFMAS
  __syncthreads();                     // drain before Cs aliases As/Bs

  {
    #pragma unroll
    for (int i = 0; i < 4; i++)
      #pragma unroll
      for (int j = 0; j < 4; j++) {
        int nloc = wn + j*16 + l15;
        float bv = ar.bias[n0 + nloc];
        #pragma unroll
        for (int r = 0; r < 4; r++) {
          int mloc = wm + i*16 + quad*4 + r;
          float val = (acc[i][j][r] + bv) * ar.scale;
          if (ar.mode == 1) Cs[mloc*136 + nloc] = f2bf(val);
          else              Cs[nloc*136 + mloc] = f2bf(val);
        }
      }
    __syncthreads();
    int bb = m0 >> 10, hh0 = n0 >> 6, mbase = m0 & 1023;
    u16* outp2 = (u16*)ar.out;
    if (ar.mode == 1) {
      #pragma unroll
      for (int p = 0; p < 8; p++) {
        int mloc = (tid >> 4) + p*16, seg = tid & 15;
        int head = hh0 + (seg >> 3);
        size_t base = ((size_t)(bb*8 + head)*1024 + mbase)*64;
        *(short8*)(outp2 + base + (size_t)mloc*64 + (seg & 7)*8) =
            *(const short8*)&Cs[mloc*136 + seg*8];
      }
    } else {
      #pragma unroll
      for (int p = 0; p < 8; p++) {
        int nloc = (tid >> 4) + p*16, seg = tid & 15;
        int head = hh0 + (nloc >> 6), d = nloc & 63;
        size_t base = (size_t)(bb*8 + head)*64*1024 + mbase;
        *(short8*)(outp2 + base + (size_t)d*1024 + seg*8) =
            *(const short8*)&Cs[nloc*136 + seg*8];
      }
    }
  }
}

// ---------------- bf16-A GEMM (Wo): unchanged R13 structure ---------------
__global__ __launch_bounds__(256, 4) void k_gemm(GArg g0, GArg g1, GArg g2) {
  GArg ar = (blockIdx.z == 0) ? g0 : (blockIdx.z == 1) ? g1 : g2;
  __shared__ char smem_[34816];
  u16* As = (u16*)smem_;
  u16* Bs = (u16*)(smem_ + 16384);
  u16* Cs = (u16*)smem_;
  int tid = threadIdx.x, lane = tid & 63, wv = tid >> 6;
  int quad = lane >> 4, l15 = lane & 15;
  int n0 = blockIdx.x * 128, m0 = blockIdx.y * 128;
  int wm = (wv >> 1) * 64, wn = (wv & 1) * 64;
  f32x4 acc[4][4];
  #pragma unroll
  for (int i = 0; i < 4; i++)
    #pragma unroll
    for (int j = 0; j < 4; j++)
      acc[i][j] = (f32x4){0.f, 0.f, 0.f, 0.f};

  const u16* Abase = ar.A  + (size_t)m0 * 512;
  const u16* Bbase = ar.Wt + (size_t)n0 * 512;
  int c0 = wv * 128;

#define STAGEG(kt, nb) do { \
    _Pragma("unroll") \
    for (int i = 0; i < 2; i++) { \
      int c = c0 + i*64 + lane; \
      GLDS16(Abase + (c >> 2)*512 + (kt)*32 + (c & 3)*8, &As[(nb)*4096 + (c0 + i*64)*8]); \
      GLDS16(Bbase + (c >> 2)*512 + (kt)*32 + (c & 3)*8, &Bs[(nb)*4096 + (c0 + i*64)*8]); \
    } } while (0)

  STAGEG(0, 0);

  for (int ks = 0; ks < 16; ks++) {
    int cur = ks & 1;
    __syncthreads();
    if (ks < 15) STAGEG(ks + 1, cur ^ 1);
    int bs = cur * 4096;
    short8 af[4], bf[4];
    #pragma unroll
    for (int i = 0; i < 4; i++) af[i] = *(const short8*)&As[bs + (wm + i*16 + l15)*32 + quad*8];
    #pragma unroll
    for (int j = 0; j < 4; j++) bf[j] = *(const short8*)&Bs[bs + (wn + j*16 + l15)*32 + quad*8];
    __builtin_amdgcn_s_setprio(1);
    #pragma unroll
    for (int i = 0; i < 4; i++)
      #pragma unroll
      for (int j = 0; j < 4; j++)
        acc[i][j] = __builtin_amdgcn_mfma_f32_16x16x32_bf16(af[i], bf[j], acc[i][j], 0, 0, 0);
    __builtin_amdgcn_s_setprio(0);
  }
#undef STAGEG
  __syncthreads();

  if (ar.mode == 0) {
    #pragma unroll
    for (int i = 0; i < 4; i++)
      #pragma unroll
      for (int j = 0; j < 4; j++) {
        int ncol = n0 + wn + j*16 + l15;
        float bv = ar.bias[ncol];
        #pragma unroll
        for (int r = 0; r < 4; r++) {
          int m = m0 + wm + i*16 + quad*4 + r;
          ((float*)ar.out)[m*512 + ncol] = (acc[i][j][r] + bv) * ar.scale;
        }
      }
  } else {
    #pragma unroll
    for (int i = 0; i < 4; i++)
      #pragma unroll
      for (int j = 0; j < 4; j++) {
        int nloc = wn + j*16 + l15;
        float bv = ar.bias[n0 + nloc];
        #pragma unroll
        for (int r = 0; r < 4; r++) {
          int mloc = wm + i*16 + quad*4 + r;
          float val = (acc[i][j][r] + bv) * ar.scale;
          if (ar.mode == 1) Cs[mloc*136 + nloc] = f2bf(val);
          else              Cs[nloc*136 + mloc] = f2bf(val);
        }
      }
    __syncthreads();
    int bb = m0 >> 10, hh0 = n0 >> 6, mbase = m0 & 1023;
    u16* outp = (u16*)ar.out;
    if (ar.mode == 1) {
      #pragma unroll
      for (int p = 0; p < 8; p++) {
        int mloc = (tid >> 4) + p*16, seg = tid & 15;
        int head = hh0 + (seg >> 3);
        size_t base = ((size_t)(bb*8 + head)*1024 + mbase)*64;
        *(short8*)(outp + base + (size_t)mloc*64 + (seg & 7)*8) =
            *(const short8*)&Cs[mloc*136 + seg*8];
      }
    } else {
      #pragma unroll
      for (int p = 0; p < 8; p++) {
        int nloc = (tid >> 4) + p*16, seg = tid & 15;
        int head = hh0 + (nloc >> 6), d = nloc & 63;
        size_t base = (size_t)(bb*8 + head)*64*1024 + mbase;
        *(short8*)(outp + base + (size_t)d*1024 + seg*8) =
            *(const short8*)&Cs[nloc*136 + seg*8];
      }
    }
  }
}

// ---------------- fused attention (unchanged from R14) ----------------
__global__ __launch_bounds__(512, 4) void k_attn(
    const u16* __restrict__ qws, const u16* __restrict__ kws, const u16* __restrict__ vtws,
    const u16* __restrict__ relk80, const u16* __restrict__ relvT,
    const float* __restrict__ tree_emb, const u32* __restrict__ packed,
    u16* __restrict__ ctx) {
  __shared__ u16 Kb[2][2048];       // [buf][32 k-rows][64 d] swizzled
  __shared__ u16 Vb[2][2048];       // [buf][64 d-rows][32 k] swizzled
  __shared__ u16 qdotL[8*16*68];    // [w][q][bucket]  (band tiles)
  __shared__ u16 PB[8][16*96];      // per-wave banded P
  __shared__ u16 Pl[8][16*40];      // per-wave C->A bridge, stride 40

  int tid = threadIdx.x, lane = tid & 63, wv = tid >> 6;
  int quad = lane >> 4, l15 = lane & 15;
  int qb = blockIdx.x, h = blockIdx.y, b = blockIdx.z;
  int q0 = qb * 128 + wv * 16;

  // register tree table: lane v (0..63) holds tree_emb[v][h] * log2e
  float treev = tree_emb[lane * 8 + h] * 1.44269504f;

  #pragma unroll
  for (int i = 0; i < 12; i++) ((u32*)&PB[wv][0])[lane + i*64] = 0u;

  const u16* qp = qws  + (size_t)(b*8 + h)*(1024*64);
  const u16* kp = kws  + (size_t)(b*8 + h)*(1024*64);
  const u16* vp = vtws + (size_t)(b*8 + h)*(64*1024);
  const u32* pkb = packed + ((size_t)b << 20);

  // staging roles: waves 0-3 carry K rows; waves 4-7 carry V rows.
  int rk = (wv & 3)*8 + (lane >> 3);
  int swk = (((lane & 7)*8) ^ ((rk & 7) << 3));
  int rv = (wv & 3)*16 + (lane >> 2);
  const u16* vsrc = vp + (size_t)rv*1024 + (((lane & 3)*8) ^ ((rv & 3) << 3));

#define STAGE(kt, nb) do { \
    if (wv < 4) GLDS16(kp + (size_t)((kt)*32 + rk)*64 + swk, &Kb[nb][wv*512]); \
    else        GLDS16(vsrc + (kt)*32, &Vb[nb][(wv & 3)*512]); \
  } while (0)

  STAGE(0, 0);

  short8 aQ[2];
  #pragma unroll
  for (int kf = 0; kf < 2; kf++)
    aQ[kf] = *(const short8*)(qp + (q0 + l15)*64 + kf*32 + quad*8);

  float qd0[4], qd64[4];
  #pragma unroll
  for (int t = 0; t < 5; t++) {
    f32x4 C = (f32x4){0.f,0.f,0.f,0.f};
    #pragma unroll
    for (int kf = 0; kf < 2; kf++) {
      short8 bR = *(const short8*)(relk80 + (t*16 + l15)*64 + kf*32 + quad*8);
      C = __builtin_amdgcn_mfma_f32_16x16x32_bf16(aQ[kf], bR, C, 0, 0, 0);
    }
    if (t == 0) {
      #pragma unroll
      for (int r = 0; r < 4; r++) qd0[r] = __shfl(C[r], lane & 48, 64);
    }
    if (t == 4) {
      #pragma unroll
      for (int r = 0; r < 4; r++) qd64[r] = __shfl(C[r], lane & 48, 64);
    }
    int col = t*16 + l15;
    if (col < 65) {
      #pragma unroll
      for (int r = 0; r < 4; r++)
        qdotL[(wv*16 + quad*4 + r)*68 + col] = f2bf(C[r]);
    }
  }

  int t_lo = max(0, (q0 - 31) >> 5);
  int t_hi = min(31, (q0 + 46) >> 5);

  // precomputed LDS read offsets (u16 units); ct adds 1024, t adds 512
  int sK = (l15 & 7) << 3;
  int kbo0 = l15*64 + ((quad*8) ^ sK);          // kf=0
  int kbo1 = l15*64 + (((4 + quad)*8) ^ sK);    // kf=1
  int vbo  = l15*32 + ((quad*8) ^ ((l15 & 3) << 3));

  u32 pk[8];
  #pragma unroll
  for (int e = 0; e < 8; e++)
    pk[e] = pkb[((q0 + quad*4 + (e & 3)) << 10) + (e >> 2)*16 + l15];

  f32x4 O[4];
  float rs[4], ts0[4], ts1[4];
  #pragma unroll
  for (int t = 0; t < 4; t++) O[t] = (f32x4){0.f,0.f,0.f,0.f};
  #pragma unroll
  for (int r = 0; r < 4; r++) { rs[r] = 0.f; ts0[r] = 0.f; ts1[r] = 0.f; }

  for (int jt = 0; jt < 32; ++jt) {
    int cur = jt & 1;
    int k0 = jt << 5;
    __syncthreads();                    // stage(jt) complete; readers of buf cur^1 done
    if (jt < 31) STAGE(jt + 1, cur ^ 1);

    u32 pkc[8];
    #pragma unroll
    for (int e = 0; e < 8; e++) pkc[e] = pk[e];
    if (jt < 31) {
      int kn = (jt + 1) << 5;
      #pragma unroll
      for (int e = 0; e < 8; e++)
        pk[e] = pkb[((q0 + quad*4 + (e & 3)) << 10) + kn + (e >> 2)*16 + l15];
    }

    short8 kr00 = *(const short8*)&Kb[cur][kbo0];
    short8 kr01 = *(const short8*)&Kb[cur][kbo1];
    short8 kr10 = *(const short8*)&Kb[cur][1024 + kbo0];
    short8 kr11 = *(const short8*)&Kb[cur][1024 + kbo1];
    short8 vr[4];
    #pragma unroll
    for (int t = 0; t < 4; t++) vr[t] = *(const short8*)&Vb[cur][t*512 + vbo];

    f32x4 S0 = (f32x4){0.f,0.f,0.f,0.f}, S1 = (f32x4){0.f,0.f,0.f,0.f};
    __builtin_amdgcn_s_setprio(1);
    S0 = __builtin_amdgcn_mfma_f32_16x16x32_bf16(aQ[0], kr00, S0, 0, 0, 0);
    S0 = __builtin_amdgcn_mfma_f32_16x16x32_bf16(aQ[1], kr01, S0, 0, 0, 0);
    S1 = __builtin_amdgcn_mfma_f32_16x16x32_bf16(aQ[0], kr10, S1, 0, 0, 0);
    S1 = __builtin_amdgcn_mfma_f32_16x16x32_bf16(aQ[1], kr11, S1, 0, 0, 0);
    __builtin_amdgcn_s_setprio(0);
    f32x4 Scur[2] = { S0, S1 };

    if (jt < t_lo) {
      #pragma unroll
      for (int ct = 0; ct < 2; ct++) {
        float pv[4];
        #pragma unroll
        for (int r = 0; r < 4; r++) {
          u32 sg = pkc[ct*4 + r];
          float rw = __uint_as_float(sg & 0xffff0000u);
          float tb = __int_as_float(__builtin_amdgcn_ds_bpermute(
              (int)((sg & 63u) << 2), __float_as_int(treev)));
          float qm = (sg & 128u) ? -1e30f : qd0[r];
          float p = fexp2(__builtin_fmaf(tb, rw, Scur[ct][r] + qm));
          ts0[r] += p;
          pv[r] = p;
        }
        u32 c01 = cvtpk(pv[0], pv[1]), c23 = cvtpk(pv[2], pv[3]);
        u16* pl = &Pl[wv][(quad*4)*40 + ct*16 + l15];
        pl[0]   = (u16)c01; pl[40]  = (u16)(c01 >> 16);
        pl[80]  = (u16)c23; pl[120] = (u16)(c23 >> 16);
      }
    } else if (jt > t_hi) {
      #pragma unroll
      for (int ct = 0; ct < 2; ct++) {
        float pv[4];
        #pragma unroll
        for (int r = 0; r < 4; r++) {
          u32 sg = pkc[ct*4 + r];
          float rw = __uint_as_float(sg & 0xffff0000u);
          float tb = __int_as_float(__builtin_amdgcn_ds_bpermute(
              (int)((sg & 63u) << 2), __float_as_int(treev)));
          float qm = (sg & 128u) ? -1e30f : qd64[r];
          float p = fexp2(__builtin_fmaf(tb, rw, Scur[ct][r] + qm));
          ts1[r] += p;
          pv[r] = p;
        }
        u32 c01 = cvtpk(pv[0], pv[1]), c23 = cvtpk(pv[2], pv[3]);
        u16* pl = &Pl[wv][(quad*4)*40 + ct*16 + l15];
        pl[0]   = (u16)c01; pl[40]  = (u16)(c01 >> 16);
        pl[80]  = (u16)c23; pl[120] = (u16)(c23 >> 16);
      }
    } else {
      #pragma unroll
      for (int ct = 0; ct < 2; ct++) {
        float pv[4];
        #pragma unroll
        for (int r = 0; r < 4; r++) {
          int kloc = ct*16 + l15, qloc = quad*4 + r;
          int d = (k0 + kloc) - (q0 + qloc);
          int bucket = min(max(d + 32, 0), 64);
          u32 sg = pkc[ct*4 + r];
          float rw = __uint_as_float(sg & 0xffff0000u);
          float tb = __int_as_float(__builtin_amdgcn_ds_bpermute(
              (int)((sg & 63u) << 2), __float_as_int(treev)));
          float qd = bf2f(qdotL[(wv*16 + qloc)*68 + bucket]);
          float qm = (sg & 128u) ? -1e30f : qd;
          float p = fexp2(__builtin_fmaf(tb, rw, Scur[ct][r] + qm));
          if (d <= -32)      ts0[r] += p;
          else if (d >= 32)  ts1[r] += p;
          else             { rs[r] += p; PB[wv][qloc*96 + d + 32] = f2bf(p); }
          pv[r] = p;
        }
        u32 c01 = cvtpk(pv[0], pv[1]), c23 = cvtpk(pv[2], pv[3]);
        u16* pl = &Pl[wv][(quad*4)*40 + ct*16 + l15];
        pl[0]   = (u16)c01; pl[40]  = (u16)(c01 >> 16);
        pl[80]  = (u16)c23; pl[120] = (u16)(c23 >> 16);
      }
    }

    {
      short8 aP = *(const short8*)&Pl[wv][l15*40 + quad*8];
      __builtin_amdgcn_s_setprio(1);
      #pragma unroll
      for (int t = 0; t < 4; t++)
        O[t] = __builtin_amdgcn_mfma_f32_16x16x32_bf16(aP, vr[t], O[t], 0, 0, 0);
      __builtin_amdgcn_s_setprio(0);
    }
  }
#undef STAGE

  #pragma unroll
  for (int m = 1; m < 16; m <<= 1) {
    #pragma unroll
    for (int r = 0; r < 4; r++) {
      rs[r]  += __shfl_xor(rs[r],  m, 64);
      ts0[r] += __shfl_xor(ts0[r], m, 64);
      ts1[r] += __shfl_xor(ts1[r], m, 64);
    }
  }
  if (l15 == 0) {
    #pragma unroll
    for (int r = 0; r < 4; r++) {
      PB[wv][(quad*4 + r)*96 + 0]  = f2bf(ts0[r]);
      PB[wv][(quad*4 + r)*96 + 64] = f2bf(ts1[r]);
    }
  }
  // PB is per-wave: ds_write -> ds_read within the same wave, no barrier.

  {
    short8 aB[3];
    #pragma unroll
    for (int s = 0; s < 3; s++)
      aB[s] = *(const short8*)&PB[wv][l15*96 + s*32 + quad*8];
    #pragma unroll
    for (int t = 0; t < 4; t++)
      #pragma unroll
      for (int s = 0; s < 3; s++) {
        short8 bRV = *(const short8*)(relvT + (t*16 + l15)*96 + s*32 + quad*8);
        O[t] = __builtin_amdgcn_mfma_f32_16x16x32_bf16(aB[s], bRV, O[t], 0, 0, 0);
      }
  }

  {
    float inv[4];
    #pragma unroll
    for (int r = 0; r < 4; r++) inv[r] = 1.0f / (rs[r] + ts0[r] + ts1[r]);
    #pragma unroll
    for (int t = 0; t < 4; t++)
      #pragma unroll
      for (int r = 0; r < 4; r++) {
        int qg = q0 + quad*4 + r;
        ctx[(b*1024 + qg)*512 + h*64 + t*16 + l15] = f2bf(O[t][r] * inv[r]);
      }
  }
}

extern "C" void kernel_launch(void* const* d_in, const int* in_sizes, int n_in,
                              void* d_out, int out_size, void* d_ws, size_t ws_size,
                              hipStream_t stream) {
  const float* key   = (const float*)d_in[0];
  const float* value = (const float*)d_in[1];
  const float* query = (const float*)d_in[2];
  const unsigned char* maskp = (const unsigned char*)d_in[3];
  const int*   relm  = (const int*)d_in[4];
  const float* relw  = (const float*)d_in[5];
  const float* Wk = (const float*)d_in[6];
  const float* bk = (const float*)d_in[7];
  const float* Wq = (const float*)d_in[8];
  const float* bq = (const float*)d_in[9];
  const float* Wv = (const float*)d_in[10];
  const float* bv = (const float*)d_in[11];
  const float* Wo = (const float*)d_in[12];
  const float* bo = (const float*)d_in[13];
  const float* rek = (const float*)d_in[14];
  const float* rev = (const float*)d_in[15];
  const float* te  = (const float*)d_in[16];
  (void)in_sizes; (void)n_in; (void)out_size;

  char* w = (char*)d_ws;
  size_t off = 0;
  auto alloc = [&](size_t bytes) -> void* {
    void* p = w + off; off += (bytes + 255) & ~(size_t)255; return p;
  };
  u16* WkT = (u16*)alloc((size_t)512*512*2);
  u16* WqT = (u16*)alloc((size_t)512*512*2);
  u16* WvT = (u16*)alloc((size_t)512*512*2);
  u16* WoT = (u16*)alloc((size_t)512*512*2);
  u16* qws = (u16*)alloc((size_t)8*8*1024*64*2);   // [B,H,L,64], pre-scaled 0.125*log2e
  u16* kws = (u16*)alloc((size_t)8*8*1024*64*2);   // [B,H,L,64]
  u16* vt  = (u16*)alloc((size_t)8*8*1024*64*2);   // [B,H,64,L]
  u32* packed = (u32*)alloc((size_t)8*1024*1024*4);
  u16* ctxb = (u16*)alloc((size_t)8192*512*2);     // [B,L,512] bf16
  u16* relk80 = (u16*)alloc((size_t)80*64*2);
  u16* relvT  = (u16*)alloc((size_t)64*96*2);
  if (off > ws_size) return;

  k_pre<<<1068, 256, 0, stream>>>(Wk, Wq, Wv, Wo, WkT, WqT, WvT, WoT,
                                  rek, rev, relk80, relvT);

  // Q pre-scaled by 0.125 * log2(e): softmax computed in exp2 domain.
  FArg aq { query, WqT, bq, (void*)qws, 1, 0.18033688f };
  FArg ak { key,   WkT, bk, (void*)kws, 1, 1.0f };
  FArg av { value, WvT, bv, (void*)vt,  2, 1.0f };
  k_gemmf<<<1792, 256, 0, stream>>>(aq, ak, av, relm, relw, maskp, packed);

  k_attn<<<dim3(8,8,8), 512, 0, stream>>>(qws, kws, vt, relk80, relvT, te, packed, ctxb);

  GArg ao { ctxb, WoT, bo, d_out, 0, 1.0f };
  k_gemm<<<dim3(4,64,1), 256, 0, stream>>>(ao, ao, ao);
}